// Round 6
// baseline (125.942 us; speedup 1.0000x reference)
//
#include <hip/hip_runtime.h>
#include <math.h>

// Lee Oscillator: per-element 100-step chaotic recurrence, time-max-pooled.
// Must match the jax/XLA-CPU f32 expected bitwise (chaotic map, ~20x/step
// error amplification). Key facts exploited:
//  * type 1 (the benched config) has a1=b1=0: L does not feed back; the
//    (E,I) trajectory depends ONLY on tanh. max_t L_t = fma(max_t D, damp,
//    omega) by monotonicity of fma -> exp accuracy is irrelevant.
//  * XLA CPU sets llvm::FPOpFusion::Fast -> ISel fuses every single-use
//    fmul+fadd into FMA. EmitFastTanh(with_fma=true) clamps at
//    +-7.99881172180175781 and the Horner chains contract to FMA.
//  * HLO simplifier does NOT fold float 0*L (NaN-unsound); ISel turns
//    fadd(fmul(0,L), fmul(5,E)) into fma(0,L,round(5E)) = round(5E), then
//    fsub(.., fmul(5,I)) -> fma(-5, I, round(5E)). a4=1: mul(1,sim0)->sim0
//    folds, leaving a PLAIN fadd (not fused). I-row: tanh(5*round(E-I)).

#define N_STEPS 100

// (a1,a2,a3,a4,b1,b2,b3,b4,xi_E,xi_I,mu,e,k) for oscillator types 1..8 (f32)
__constant__ float PAR[8][13] = {
    { 0.0f,  5.0f,  5.0f,  1.0f,  0.0f, -1.0f,  1.0f,  0.0f, 0.0f, 0.0f, 5.0f, 0.001f, 500.0f},
    { 0.5f,  0.55f, 0.55f, -0.5f,  0.5f, -0.55f, -0.55f, -0.5f, 0.0f, 0.0f, 1.0f, 0.001f, 50.0f},
    { 0.5f,  0.6f,  0.55f,  0.5f, -0.5f, -0.6f,  -0.55f,  0.5f, 0.0f, 0.0f, 1.0f, 0.001f, 50.0f},
    {-0.5f,  0.55f, 0.55f, -0.5f, -0.5f, -0.55f, -0.55f,  0.5f, 0.0f, 0.0f, 1.0f, 0.001f, 50.0f},
    {-0.9f,  0.9f,  0.9f,  -0.9f,  0.9f, -0.9f,  -0.9f,   0.9f, 0.0f, 0.0f, 1.0f, 0.001f, 50.0f},
    {-0.9f,  0.9f,  0.9f,  -0.9f,  0.9f, -0.9f,  -0.9f,   0.9f, 0.0f, 0.0f, 1.0f, 0.001f, 300.0f},
    {-5.0f,  5.0f,  5.0f,  -5.0f,  1.0f, -1.0f,  -1.0f,   1.0f, 0.0f, 0.0f, 1.0f, 0.001f, 50.0f},
    {-5.0f,  5.0f,  5.0f,  -5.0f,  1.0f, -1.0f,  -1.0f,   1.0f, 0.0f, 0.0f, 1.0f, 0.001f, 300.0f},
};

// XLA CPU f32 tanh (llvm_ir::EmitFastTanh, with_fma=true):
// clamp +-7.99881172180175781, FMA-contracted Horner, IEEE divide,
// |x| < 0.0004 -> x (selected on the UNclamped input).
__device__ __forceinline__ float xla_tanhf(float x) {
#pragma clang fp contract(off)
    float ax = fabsf(x);
    float xc = fminf(fmaxf(x, -7.99881172180175781f), 7.99881172180175781f);
    float x2 = xc * xc;
    float p = -2.76076847742355e-16f;
    p = fmaf(p, x2, 2.00018790482477e-13f);
    p = fmaf(p, x2, -8.60467152213735e-11f);
    p = fmaf(p, x2, 5.12229709037114e-08f);
    p = fmaf(p, x2, 1.48572235717979e-05f);
    p = fmaf(p, x2, 6.37261928875436e-04f);
    p = fmaf(p, x2, 4.89352455891786e-03f);
    float num = xc * p;
    float q = 1.19825839466702e-06f;
    q = fmaf(q, x2, 1.18534705686654e-04f);
    q = fmaf(q, x2, 2.26843463243900e-03f);
    q = fmaf(q, x2, 4.89352518554385e-03f);
    float r = num / q;                       // IEEE f32 divide
    return (ax < 0.0004f) ? x : r;
}

// XLA CPU f32 exp (GenerateVF32Exp, Cephes/Eigen), FMA-contracted by ISel.
// Accuracy only needs to be ~ulp here (type 1: damp never feeds the chaos).
__device__ __forceinline__ float xla_expf(float x) {
#pragma clang fp contract(off)
    float xc = fminf(fmaxf(x, -88.3762626647949f), 88.3762626647950f);
    float fx = floorf(fmaf(xc, 1.44269504088896341f, 0.5f));
    float r = fmaf(fx, -0.693359375f, xc);
    r = fmaf(fx, 2.12194440e-4f, r);
    float r2 = r * r;
    float y = 1.9875691500e-4f;
    y = fmaf(y, r, 1.3981999507e-3f);
    y = fmaf(y, r, 8.3334519073e-3f);
    y = fmaf(y, r, 4.1665795894e-2f);
    y = fmaf(y, r, 1.6666665459e-1f);
    y = fmaf(y, r, 5.0000001201e-1f);
    y = fmaf(y, r2, r);
    y = y + 1.0f;
    int n2 = (int)fx;
    float p2n = __int_as_float((n2 + 127) << 23);   // n=-127 -> +0.0
    return y * p2n;
}

__global__ __launch_bounds__(256)
void lee_oscillator_kernel(const float* __restrict__ x,
                           const int* __restrict__ osc_type,
                           float* __restrict__ out, int n)
{
#pragma clang fp contract(off)
    int i = blockIdx.x * 256 + threadIdx.x;
    if (i >= n) return;

    int t = *osc_type;                 // uniform across grid
    const float* p = PAR[t - 1];
    float a1 = p[0], a2 = p[1], a3 = p[2], a4 = p[3];
    float b1 = p[4], b2 = p[5], b3 = p[6], b4 = p[7];
    float xiE = p[8], xiI = p[9], mu = p[10], e = p[11], k = p[12];

    float xv   = x[i];
    float sgn  = (xv > 0.0f) ? 1.0f : ((xv < 0.0f) ? -1.0f : 0.0f);
    float sim0 = fmaf(e, sgn, xv);                 // fadd(x, fmul(e,sgn)) fused

    float targ  = (-k * sim0) * sim0;              // two plain muls
    float damp  = xla_expf(targ);
    float omega = xla_tanhf(mu * sim0);

    if (t == 1) {
        // Specialized bitwise-XLA path (a1=b1=0, a4=1, b2=-1, b3=1, xi=0).
        if (damp == 0.0f) {            // L == omega bitwise every step
            out[i] = omega;
            return;
        }
        float E = 0.2f, I = 0.0f;
        float Dmax = -INFINITY;
        for (int s = 0; s < N_STEPS; ++s) {
            float tE   = 5.0f * E;                 // round(a2*E)
            float uE   = fmaf(-5.0f, I, tE);       // fnma with a3
            float sE   = uE + sim0;                // plain fadd (a4==1 folded)
            float argE = 5.0f * sE;                // mu *
            float vI   = E - I;                    // plain fsub
            float argI = 5.0f * vI;
            float E1 = xla_tanhf(argE);
            float I1 = xla_tanhf(argI);
            float D  = E1 - I1;                    // plain fsub
            Dmax = fmaxf(Dmax, D);
            E = E1; I = I1;
        }
        out[i] = fmaf(Dmax, damp, omega);          // = max_t fma(D_t,damp,omega)
        return;
    }

    // Generic path (other oscillator types), same fusion discipline.
    float nb2 = -b2;
    float E = 0.2f, I = 0.0f, L = 0.2f;
    float m = -INFINITY;
    for (int s = 0; s < N_STEPS; ++s) {
        float tE = a2 * E;
        float uE = fmaf(a1, L, tE);
        uE = fmaf(-a3, I, uE);
        uE = fmaf(a4, sim0, uE);
        uE = uE - xiE;
        float argE = mu * uE;
        float tI = nb2 * E;
        float uI = fmaf(b1, L, tI);
        uI = fmaf(-b3, I, uI);
        uI = fmaf(b4, sim0, uI);
        uI = uI - xiI;
        float argI = mu * uI;
        float E1 = xla_tanhf(argE);
        float I1 = xla_tanhf(argI);
        float d = E1 - I1;
        L = fmaf(d, damp, omega);
        E = E1; I = I1;
        m = fmaxf(m, L);
    }
    out[i] = m;
}

extern "C" void kernel_launch(void* const* d_in, const int* in_sizes, int n_in,
                              void* d_out, int out_size, void* d_ws, size_t ws_size,
                              hipStream_t stream) {
    const float* x        = (const float*)d_in[0];
    const int*   osc_type = (const int*)d_in[1];
    float*       out      = (float*)d_out;
    int n = in_sizes[0];

    int blocks = (n + 255) / 256;
    lee_oscillator_kernel<<<blocks, 256, 0, stream>>>(x, osc_type, out, n);
}